// Round 1
// baseline (269.305 us; speedup 1.0000x reference)
//
#include <hip/hip_runtime.h>
#include <cstdint>
#include <cstddef>

// Sizes (compile-time constants for this problem)
// B=16, T=8, K=4, DIN=9408, H1=1024, F=512, MH=128

// ---------------- 4x4 average pool: x(16,3,224,224) -> xp(16,9408) ----------------
__global__ void pool_kernel(const float* __restrict__ x, float* __restrict__ xp) {
  int idx = blockIdx.x * 256 + threadIdx.x;      // 150528 total = 16*3*56*56
  int bc = idx / 3136;                            // b*3+c
  int r  = idx - bc * 3136;
  int i  = r / 56;
  int j  = r - i * 56;
  const float* src = x + ((size_t)bc * 224 + 4 * i) * 224 + 4 * j;
  float s = 0.f;
#pragma unroll
  for (int rr = 0; rr < 4; ++rr) {
    float4 v = *reinterpret_cast<const float4*>(src + rr * 224);
    s += v.x + v.y + v.z + v.w;
  }
  xp[idx] = s * 0.0625f;
}

// ---------------- generic split-K skinny GEMM (M = 16 fixed) ----------------
// C[b,j] = sum_k A'[b,k] * B[k,j], A'[b,k] optionally scaled by coefs4[b*32+t*4]
// Partials written per K-chunk: P[chunk][16][N]. blockIdx.x = chunk, .y = j-group.
// Chunks >= chunkSplit use (A2, ldA2, B2) unscaled (second K segment).
template<int KC, int VEC>
__global__ __launch_bounds__(256) void skinny_gemm(
    const float* __restrict__ A, int ldA,
    const float* __restrict__ B,
    const float* __restrict__ A2, int ldA2,
    const float* __restrict__ B2,
    int chunkSplit, int chunksPerT,
    const float* __restrict__ coefs4,
    int N, float* __restrict__ P)
{
  __shared__ float a_s[KC * 20];   // [kk][b] with stride 20 (16B-aligned rows, pad kills pow2)
  const int c = blockIdx.x;

  const float* Ab;
  const float* Bb;
  int lda, iLoc0, t = 0;
  bool scaled;
  if (c < chunkSplit) {
    Ab = A; lda = ldA;
    if (chunksPerT > 0) {
      t = c / chunksPerT;
      iLoc0 = (c - t * chunksPerT) * KC;
      scaled = true;
    } else {
      iLoc0 = c * KC;
      scaled = false;
    }
    Bb = B + (size_t)c * KC * N;
  } else {
    Ab = A2; lda = ldA2;
    iLoc0 = (c - chunkSplit) * KC;
    scaled = false;
    Bb = B2 + (size_t)iLoc0 * N;
  }

  // Stage A-chunk (scaled) into LDS: a_s[kk*20 + b]
  for (int b = 0; b < 16; ++b) {
    float s = scaled ? coefs4[b * 32 + t * 4] : 1.f;
    const float* Arow = Ab + (size_t)b * lda + iLoc0;
    for (int idx = threadIdx.x; idx < KC; idx += 256)
      a_s[idx * 20 + b] = s * Arow[idx];
  }
  __syncthreads();

  const int j0 = (blockIdx.y * 256 + threadIdx.x) * VEC;
  const float* Brow = Bb + j0;

  float acc[16][VEC];
#pragma unroll
  for (int b = 0; b < 16; ++b)
#pragma unroll
    for (int v = 0; v < VEC; ++v) acc[b][v] = 0.f;

#pragma unroll 2
  for (int kk = 0; kk < KC; ++kk) {
    float w[VEC];
    if constexpr (VEC == 1) {
      w[0] = *Brow;
    } else {
      float2 t2 = *reinterpret_cast<const float2*>(Brow);
      w[0] = t2.x; w[1] = t2.y;
    }
    Brow += N;
    const float4 a0 = *reinterpret_cast<const float4*>(&a_s[kk * 20 + 0]);
    const float4 a1 = *reinterpret_cast<const float4*>(&a_s[kk * 20 + 4]);
    const float4 a2 = *reinterpret_cast<const float4*>(&a_s[kk * 20 + 8]);
    const float4 a3 = *reinterpret_cast<const float4*>(&a_s[kk * 20 + 12]);
    const float av[16] = {a0.x, a0.y, a0.z, a0.w, a1.x, a1.y, a1.z, a1.w,
                          a2.x, a2.y, a2.z, a2.w, a3.x, a3.y, a3.z, a3.w};
#pragma unroll
    for (int b = 0; b < 16; ++b)
#pragma unroll
      for (int v = 0; v < VEC; ++v)
        acc[b][v] = fmaf(av[b], w[v], acc[b][v]);
  }

  float* Pb = P + (size_t)c * 16 * N + j0;
#pragma unroll
  for (int b = 0; b < 16; ++b) {
#pragma unroll
    for (int v = 0; v < VEC; ++v) Pb[v] = acc[b][v];
    Pb += N;
  }
}

// ---------------- reductions / epilogues ----------------
__global__ void reduce1_kernel(const float* __restrict__ P, const float* __restrict__ b1,
                               float* __restrict__ z1, float* __restrict__ t1) {
  int f = blockIdx.x * 256 + threadIdx.x;   // 16384
  float s = b1[f & 1023];
  const float* p = P + f;
#pragma unroll 8
  for (int c = 0; c < 64; ++c) { s += *p; p += 16384; }
  z1[f] = s;
  t1[f] = fmaxf(s, 0.f);
}

__global__ void reduce2_kernel(const float* __restrict__ P, const float* __restrict__ b2,
                               float* __restrict__ base) {
  int f = blockIdx.x * 256 + threadIdx.x;   // 8192
  float s = b2[f & 511];
  const float* p = P + f;
#pragma unroll 8
  for (int c = 0; c < 32; ++c) { s += *p; p += 8192; }
  base[f] = s;
}

__global__ void m_kernel(const float* __restrict__ base, const float* __restrict__ mW1,
                         const float* __restrict__ mb1, float* __restrict__ m) {
  __shared__ float bs[512];
  int b = blockIdx.x;                        // 16 blocks x 128 threads
  for (int i = threadIdx.x; i < 512; i += 128) bs[i] = base[b * 512 + i];
  __syncthreads();
  int col = threadIdx.x;
  float acc = mb1[col];
  for (int k = 0; k < 512; ++k) acc = fmaf(bs[k], mW1[k * 128 + col], acc);
  m[b * 128 + col] = fmaxf(acc, 0.f);
}

__global__ void coef_kernel(const float* __restrict__ m, const float* __restrict__ mW2,
                            const float* __restrict__ mb2, float* __restrict__ coefs) {
  int tid = threadIdx.x;                     // 512 threads, 1 block
  int b = tid >> 5, o = tid & 31;
  float acc = mb2[o];
  const float* mr = m + b * 128;
  for (int k = 0; k < 128; ++k) acc = fmaf(mr[k], mW2[k * 32 + o], acc);
  coefs[b * 32 + o] = acc;
}

__global__ void reduce3_kernel(const float* __restrict__ P, const float* __restrict__ z1,
                               const float* __restrict__ coefs, const float* __restrict__ db1,
                               float* __restrict__ h) {
  int f = blockIdx.x * 256 + threadIdx.x;   // 16384
  int b = f >> 10, j = f & 1023;
  float s = z1[f];
  const float* p = P + f;
#pragma unroll 8
  for (int c = 0; c < 256; ++c) { s += *p; p += 16384; }
#pragma unroll
  for (int t = 0; t < 8; ++t) s = fmaf(coefs[b * 32 + t * 4 + 1], db1[t * 1024 + j], s);
  h[f] = fmaxf(s, 0.f);
}

__global__ void reduce4_kernel(const float* __restrict__ P, const float* __restrict__ b2,
                               const float* __restrict__ coefs, const float* __restrict__ db2,
                               float* __restrict__ out) {
  int f = blockIdx.x * 256 + threadIdx.x;   // 8192
  int b = f >> 9, k = f & 511;
  float s = b2[k];
  const float* p = P + f;
#pragma unroll 8
  for (int c = 0; c < 144; ++c) { s += *p; p += 8192; }
#pragma unroll
  for (int t = 0; t < 8; ++t) s = fmaf(coefs[b * 32 + t * 4 + 3], db2[t * 512 + k], s);
  out[f] = s;
}

extern "C" void kernel_launch(void* const* d_in, const int* in_sizes, int n_in,
                              void* d_out, int out_size, void* d_ws, size_t ws_size,
                              hipStream_t stream) {
  const float* x   = (const float*)d_in[0];
  const float* W1  = (const float*)d_in[1];
  const float* b1  = (const float*)d_in[2];
  const float* W2  = (const float*)d_in[3];
  const float* b2  = (const float*)d_in[4];
  const float* dW1 = (const float*)d_in[5];
  const float* db1 = (const float*)d_in[6];
  const float* dW2 = (const float*)d_in[7];
  const float* db2 = (const float*)d_in[8];
  const float* mW1 = (const float*)d_in[9];
  const float* mb1 = (const float*)d_in[10];
  const float* mW2 = (const float*)d_in[11];
  const float* mb2 = (const float*)d_in[12];
  float* out = (float*)d_out;

  float* ws    = (float*)d_ws;
  float* xp    = ws;                 // 150528
  float* z1    = xp + 150528;        // 16384
  float* t1    = z1 + 16384;         // 16384
  float* base  = t1 + 16384;         // 8192
  float* mbuf  = base + 8192;        // 2048
  float* coefs = mbuf + 2048;        // 512
  float* h     = coefs + 512;        // 16384
  float* P1    = h + 16384;          // 64*16*1024  = 1048576
  float* P2    = P1 + 1048576;       // 32*16*512   = 262144
  float* P3    = P2 + 262144;        // 256*16*1024 = 4194304
  float* P4    = P3 + 4194304;       // 144*16*512  = 1179648
  // total ~8.23M floats = 32.9 MB of ws

  const int BIG = 1 << 30;

  // xp = pool(x)
  pool_kernel<<<588, 256, 0, stream>>>(x, xp);

  // z1/t1 = xp @ W1 + b1 ; relu   (K=9408, KC=147 -> 64 chunks, N=1024 in 4 j-groups)
  skinny_gemm<147, 1><<<dim3(64, 4), 256, 0, stream>>>(
      xp, 9408, W1, nullptr, 0, nullptr, BIG, 0, nullptr, 1024, P1);
  reduce1_kernel<<<64, 256, 0, stream>>>(P1, b1, z1, t1);

  // base = t1 @ W2 + b2   (K=1024, KC=32 -> 32 chunks, N=512 in 2 j-groups)
  skinny_gemm<32, 1><<<dim3(32, 2), 256, 0, stream>>>(
      t1, 1024, W2, nullptr, 0, nullptr, BIG, 0, nullptr, 512, P2);
  reduce2_kernel<<<32, 256, 0, stream>>>(P2, b2, base);

  // coefs = (relu(base @ mW1 + mb1)) @ mW2 + mb2
  m_kernel<<<16, 128, 0, stream>>>(base, mW1, mb1, mbuf);
  coef_kernel<<<1, 512, 0, stream>>>(mbuf, mW2, mb2, coefs);

  // hc = sum_{t,i} (cW1[b,t]*xp[b,i]) * dW1[t,i,j]
  // K=75264, KC=294 -> 256 chunks (32 per t, scaled staging), N=1024 in 2 j-groups (float2)
  skinny_gemm<294, 2><<<dim3(256, 2), 256, 0, stream>>>(
      xp, 9408, dW1, nullptr, 0, nullptr, BIG, 32, coefs /* +0 => cW1 */, 1024, P3);
  reduce3_kernel<<<64, 256, 0, stream>>>(P3, z1, coefs, db1, h);

  // out_pre = sum_{t,j} (cW2[b,t]*h[b,j]) * dW2[t,j,k]  +  h @ W2
  // segment1: 128 chunks (KC=64) over dW2, scaled; segment2: 16 chunks over W2, unscaled
  skinny_gemm<64, 1><<<dim3(144, 2), 256, 0, stream>>>(
      h, 1024, dW2, h, 1024, W2, 128, 16, coefs + 2 /* cW2 */, 512, P4);
  reduce4_kernel<<<32, 256, 0, stream>>>(P4, b2, coefs, db2, out);
}

// Round 2
// 183.729 us; speedup vs baseline: 1.4658x; 1.4658x over previous
//
#include <hip/hip_runtime.h>
#include <cstdint>
#include <cstddef>

// Sizes: B=16, T=8, K=4, DIN=9408, H1=1024, F=512, MH=128

// ---------------- 4x4 average pool: x(16,3,224,224) -> xp(16,9408) ----------------
__global__ void pool_kernel(const float* __restrict__ x, float* __restrict__ xp) {
  int idx = blockIdx.x * 256 + threadIdx.x;      // 150528 total = 16*3*56*56
  int bc = idx / 3136;                            // b*3+c
  int r  = idx - bc * 3136;
  int i  = r / 56;
  int j  = r - i * 56;
  const float* src = x + ((size_t)bc * 224 + 4 * i) * 224 + 4 * j;
  float s = 0.f;
#pragma unroll
  for (int rr = 0; rr < 4; ++rr) {
    float4 v = *reinterpret_cast<const float4*>(src + rr * 224);
    s += v.x + v.y + v.z + v.w;
  }
  xp[idx] = s * 0.0625f;
}

// ---------------- split-K skinny GEMM (M=16), software-pipelined ----------------
// C[b,j] = sum_k A'[b,k]*B[k,j]; A' optionally scaled by coefs4[b*32+t*4].
// Partials: P[chunk][16][N]. blockIdx.x = chunk, .y = j-group.
// Chunks >= chunkSplit use (A2, ldA2, B2) unscaled (second K segment).
template<int KC, int VEC, int UF>
__global__ __launch_bounds__(256) void skinny_gemm(
    const float* __restrict__ A, int ldA,
    const float* __restrict__ B,
    const float* __restrict__ A2, int ldA2,
    const float* __restrict__ B2,
    int chunkSplit, int chunksPerT,
    const float* __restrict__ coefs4,
    int N, float* __restrict__ P)
{
  static_assert(KC % UF == 0 && ((KC / UF) % 2 == 0), "pipeline needs even group count");
  __shared__ float a_s[KC * 20];   // [kk][b], stride 20 (pad kills pow2; reads are broadcast)
  const int c = blockIdx.x;

  const float* Ab;
  const float* Bb;
  int lda, iLoc0, t = 0;
  bool scaled;
  if (c < chunkSplit) {
    Ab = A; lda = ldA;
    if (chunksPerT > 0) {
      t = c / chunksPerT;
      iLoc0 = (c - t * chunksPerT) * KC;
      scaled = true;
    } else {
      iLoc0 = c * KC;
      scaled = false;
    }
    Bb = B + (size_t)c * KC * N;
  } else {
    Ab = A2; lda = ldA2;
    iLoc0 = (c - chunkSplit) * KC;
    scaled = false;
    Bb = B2 + (size_t)iLoc0 * N;
  }

  // Stage (scaled) A-chunk into LDS: a_s[kk*20 + b]
  for (int idx = threadIdx.x; idx < 16 * KC; idx += 256) {
    int b = idx / KC, kk = idx - b * KC;
    float s = scaled ? coefs4[b * 32 + t * 4] : 1.f;
    a_s[kk * 20 + b] = s * Ab[(size_t)b * lda + iLoc0 + kk];
  }
  __syncthreads();

  const int j0 = (blockIdx.y * 256 + threadIdx.x) * VEC;
  const float* Brow = Bb + j0;

  float acc[16][VEC];
#pragma unroll
  for (int b = 0; b < 16; ++b)
#pragma unroll
    for (int v = 0; v < VEC; ++v) acc[b][v] = 0.f;

  float w0[UF][VEC], w1[UF][VEC];

  auto loadg = [&](float (&W)[UF][VEC], int kb) {
#pragma unroll
    for (int u = 0; u < UF; ++u) {
      const float* p = Brow + (size_t)(kb + u) * N;
      if constexpr (VEC == 1) { W[u][0] = p[0]; }
      else { float2 t2 = *reinterpret_cast<const float2*>(p); W[u][0] = t2.x; W[u][1] = t2.y; }
    }
  };
  auto comp = [&](const float (&W)[UF][VEC], int kb) {
#pragma unroll
    for (int u = 0; u < UF; ++u) {
      int kk = kb + u;
      const float4 a0 = *reinterpret_cast<const float4*>(&a_s[kk * 20 + 0]);
      const float4 a1 = *reinterpret_cast<const float4*>(&a_s[kk * 20 + 4]);
      const float4 a2 = *reinterpret_cast<const float4*>(&a_s[kk * 20 + 8]);
      const float4 a3 = *reinterpret_cast<const float4*>(&a_s[kk * 20 + 12]);
      const float av[16] = {a0.x, a0.y, a0.z, a0.w, a1.x, a1.y, a1.z, a1.w,
                            a2.x, a2.y, a2.z, a2.w, a3.x, a3.y, a3.z, a3.w};
#pragma unroll
      for (int b = 0; b < 16; ++b)
#pragma unroll
        for (int v = 0; v < VEC; ++v)
          acc[b][v] = fmaf(av[b], W[u][v], acc[b][v]);
    }
  };

  constexpr int NG = KC / UF;
  loadg(w0, 0);
#pragma unroll 1
  for (int g = 0; g + 2 < NG; g += 2) {
    loadg(w1, (g + 1) * UF);   // next group in flight while computing current
    comp(w0, g * UF);
    loadg(w0, (g + 2) * UF);
    comp(w1, (g + 1) * UF);
  }
  loadg(w1, (NG - 1) * UF);
  comp(w0, (NG - 2) * UF);
  comp(w1, (NG - 1) * UF);

  float* Pb = P + (size_t)c * 16 * N + j0;
#pragma unroll
  for (int b = 0; b < 16; ++b) {
#pragma unroll
    for (int v = 0; v < VEC; ++v) Pb[v] = acc[b][v];
    Pb += N;
  }
}

// ---------------- reductions / epilogues ----------------
// Stage A: sum a group of chunks. grid (ftot/256, G)
__global__ void reduceA_kernel(const float* __restrict__ P, int nchunks_per_g, int ftot,
                               float* __restrict__ Pb) {
  int f = blockIdx.x * 256 + threadIdx.x;
  int g = blockIdx.y;
  const float* p = P + (size_t)g * nchunks_per_g * ftot + f;
  float s = 0.f;
#pragma unroll 8
  for (int c = 0; c < nchunks_per_g; ++c) { s += *p; p += ftot; }
  Pb[(size_t)g * ftot + f] = s;
}

__global__ void final1_kernel(const float* __restrict__ Pb, const float* __restrict__ b1,
                              float* __restrict__ z1, float* __restrict__ t1) {
  int f = blockIdx.x * 256 + threadIdx.x;   // 16384
  float s = b1[f & 1023] + Pb[f] + Pb[16384 + f] + Pb[32768 + f] + Pb[49152 + f];
  z1[f] = s;
  t1[f] = fmaxf(s, 0.f);
}

__global__ void reduce2_kernel(const float* __restrict__ P, const float* __restrict__ b2,
                               float* __restrict__ base) {
  int f = blockIdx.x * 256 + threadIdx.x;   // 8192
  float s = b2[f & 511];
  const float* p = P + f;
#pragma unroll 8
  for (int c = 0; c < 32; ++c) { s += *p; p += 8192; }
  base[f] = s;
}

// coefs = (relu(base@mW1+mb1))@mW2+mb2, one block of 512
__global__ __launch_bounds__(512) void mcoef_kernel(
    const float* __restrict__ base, const float* __restrict__ mW1, const float* __restrict__ mb1,
    const float* __restrict__ mW2, const float* __restrict__ mb2, float* __restrict__ coefs) {
  __shared__ float bs[16 * 512];
  __shared__ float ms[16 * 128];
  int tid = threadIdx.x;
  for (int i = tid; i < 8192; i += 512) bs[i] = base[i];
  __syncthreads();
#pragma unroll
  for (int p = 0; p < 4; ++p) {
    int o = p * 512 + tid;          // 2048 outputs of m
    int b = o >> 7, col = o & 127;
    float acc = mb1[col];
    const float* br = &bs[b * 512];
    for (int k = 0; k < 512; ++k) acc = fmaf(br[k], mW1[k * 128 + col], acc);
    ms[o] = fmaxf(acc, 0.f);
  }
  __syncthreads();
  int b = tid >> 5, o = tid & 31;
  float acc = mb2[o];
  const float* mr = &ms[b * 128];
  for (int k = 0; k < 128; ++k) acc = fmaf(mr[k], mW2[k * 32 + o], acc);
  coefs[b * 32 + o] = acc;
}

__global__ void final3_kernel(const float* __restrict__ Pb, const float* __restrict__ z1,
                              const float* __restrict__ coefs, const float* __restrict__ db1,
                              float* __restrict__ h) {
  int f = blockIdx.x * 256 + threadIdx.x;   // 16384
  int b = f >> 10, j = f & 1023;
  float s = z1[f] + Pb[f] + Pb[16384 + f] + Pb[32768 + f] + Pb[49152 + f];
#pragma unroll
  for (int t = 0; t < 8; ++t) s = fmaf(coefs[b * 32 + t * 4 + 1], db1[t * 1024 + j], s);
  h[f] = fmaxf(s, 0.f);
}

__global__ void final4_kernel(const float* __restrict__ Pb, const float* __restrict__ b2,
                              const float* __restrict__ coefs, const float* __restrict__ db2,
                              float* __restrict__ out) {
  int f = blockIdx.x * 256 + threadIdx.x;   // 8192
  int b = f >> 9, k = f & 511;
  float s = b2[k] + Pb[f] + Pb[8192 + f] + Pb[16384 + f] + Pb[24576 + f];
#pragma unroll
  for (int t = 0; t < 8; ++t) s = fmaf(coefs[b * 32 + t * 4 + 3], db2[t * 512 + k], s);
  out[f] = s;
}

extern "C" void kernel_launch(void* const* d_in, const int* in_sizes, int n_in,
                              void* d_out, int out_size, void* d_ws, size_t ws_size,
                              hipStream_t stream) {
  const float* x   = (const float*)d_in[0];
  const float* W1  = (const float*)d_in[1];
  const float* b1  = (const float*)d_in[2];
  const float* W2  = (const float*)d_in[3];
  const float* b2  = (const float*)d_in[4];
  const float* dW1 = (const float*)d_in[5];
  const float* db1 = (const float*)d_in[6];
  const float* dW2 = (const float*)d_in[7];
  const float* db2 = (const float*)d_in[8];
  const float* mW1 = (const float*)d_in[9];
  const float* mb1 = (const float*)d_in[10];
  const float* mW2 = (const float*)d_in[11];
  const float* mb2 = (const float*)d_in[12];
  float* out = (float*)d_out;

  float* ws    = (float*)d_ws;
  float* xp    = ws;                 // 150528
  float* z1    = xp + 150528;        // 16384
  float* t1    = z1 + 16384;         // 16384
  float* base  = t1 + 16384;         // 8192
  float* coefs = base + 8192;        // 512
  float* h     = coefs + 512;        // 16384
  float* P1    = h + 16384;          // 196*16*1024 = 3211264
  float* P1b   = P1 + 3211264;       // 4*16384
  float* P2    = P1b + 65536;        // 32*16*512 = 262144
  float* P3    = P2 + 262144;        // 392*16*1024 = 6422528
  float* P3b   = P3 + 6422528;       // 4*16384
  float* P4    = P3b + 65536;        // 288*16*512 = 2359296
  float* P4b   = P4 + 2359296;       // 4*8192
  // total ~12.6M floats ~ 50.5 MB of ws

  const int BIG = 1 << 30;

  // xp = pool(x)
  pool_kernel<<<588, 256, 0, stream>>>(x, xp);

  // z1/t1 = xp @ W1 + b1; relu.  K=9408, KC=48 -> 196 chunks, 4 j-groups -> 784 blocks
  skinny_gemm<48, 1, 8><<<dim3(196, 4), 256, 0, stream>>>(
      xp, 9408, W1, nullptr, 0, nullptr, BIG, 0, nullptr, 1024, P1);
  reduceA_kernel<<<dim3(64, 4), 256, 0, stream>>>(P1, 49, 16384, P1b);
  final1_kernel<<<64, 256, 0, stream>>>(P1b, b1, z1, t1);

  // base = t1 @ W2 + b2.  K=1024, KC=32 -> 32 chunks, 2 j-groups
  skinny_gemm<32, 1, 8><<<dim3(32, 2), 256, 0, stream>>>(
      t1, 1024, W2, nullptr, 0, nullptr, BIG, 0, nullptr, 512, P2);
  reduce2_kernel<<<32, 256, 0, stream>>>(P2, b2, base);

  // coefs
  mcoef_kernel<<<1, 512, 0, stream>>>(base, mW1, mb1, mW2, mb2, coefs);

  // hc = sum_{t,i} (cW1[b,t]*xp[b,i]) * dW1[t,i,j]
  // K=75264, KC=192 -> 392 chunks (49 per t), 2 j-groups (float2) -> 784 blocks
  skinny_gemm<192, 2, 8><<<dim3(392, 2), 256, 0, stream>>>(
      xp, 9408, dW1, nullptr, 0, nullptr, BIG, 49, coefs /* cW1 */, 1024, P3);
  reduceA_kernel<<<dim3(64, 4), 256, 0, stream>>>(P3, 98, 16384, P3b);
  final3_kernel<<<64, 256, 0, stream>>>(P3b, z1, coefs, db1, h);

  // out_pre = sum_{t,j}(cW2[b,t]*h[b,j])*dW2[t,j,k] + h@W2
  // seg1: 256 chunks (KC=32, 32/t) over dW2 scaled; seg2: 32 chunks over W2
  skinny_gemm<32, 1, 8><<<dim3(288, 2), 256, 0, stream>>>(
      h, 1024, dW2, h, 1024, W2, 256, 32, coefs + 2 /* cW2 */, 512, P4);
  reduceA_kernel<<<dim3(32, 4), 256, 0, stream>>>(P4, 72, 8192, P4b);
  final4_kernel<<<32, 256, 0, stream>>>(P4b, b2, coefs, db2, out);
}

// Round 3
// 173.952 us; speedup vs baseline: 1.5482x; 1.0562x over previous
//
#include <hip/hip_runtime.h>
#include <cstdint>
#include <cstddef>

// Sizes: B=16, T=8, K=4, DIN=9408, H1=1024, F=512, MH=128

// ---------------- 4x4 average pool: x(16,3,224,224) -> xp(16,9408) ----------------
__global__ void pool_kernel(const float* __restrict__ x, float* __restrict__ xp) {
  int idx = blockIdx.x * 256 + threadIdx.x;      // 150528 total = 16*3*56*56
  int bc = idx / 3136;                            // b*3+c
  int r  = idx - bc * 3136;
  int i  = r / 56;
  int j  = r - i * 56;
  const float* src = x + ((size_t)bc * 224 + 4 * i) * 224 + 4 * j;
  float s = 0.f;
#pragma unroll
  for (int rr = 0; rr < 4; ++rr) {
    float4 v = *reinterpret_cast<const float4*>(src + rr * 224);
    s += v.x + v.y + v.z + v.w;
  }
  xp[idx] = s * 0.0625f;
}

// ---------------- split-K skinny GEMM (M=16), software-pipelined ----------------
// C[b,j] = sum_k A'[b,k]*B[k,j]; A' optionally scaled by coefs4[b*32+t*4].
// Partials: P[chunk][16][N]. blockIdx.x = chunk, .y = j-group.
// Chunks >= chunkSplit use (A2, ldA2, B2) unscaled (second K segment).
template<int KC, int VEC, int UF>
__global__ __launch_bounds__(256) void skinny_gemm(
    const float* __restrict__ A, int ldA,
    const float* __restrict__ B,
    const float* __restrict__ A2, int ldA2,
    const float* __restrict__ B2,
    int chunkSplit, int chunksPerT,
    const float* __restrict__ coefs4,
    int N, float* __restrict__ P)
{
  static_assert(KC % UF == 0, "UF must divide KC");
  constexpr int NG = KC / UF;
  static_assert(NG >= 2, "need at least 2 groups");
  __shared__ float a_s[KC * 20];   // [kk][b], stride 20; comp reads are wave-uniform broadcast
  const int c = blockIdx.x;

  const float* Ab;
  const float* Bb;
  int lda, iLoc0, t = 0;
  bool scaled;
  if (c < chunkSplit) {
    Ab = A; lda = ldA;
    if (chunksPerT > 0) {
      t = c / chunksPerT;
      iLoc0 = (c - t * chunksPerT) * KC;
      scaled = true;
    } else {
      iLoc0 = c * KC;
      scaled = false;
    }
    Bb = B + (size_t)c * KC * N;
  } else {
    Ab = A2; lda = ldA2;
    iLoc0 = (c - chunkSplit) * KC;
    scaled = false;
    Bb = B2 + (size_t)iLoc0 * N;
  }

  // Stage (scaled) A-chunk into LDS: a_s[kk*20 + b] (coalesced per row)
  for (int b = 0; b < 16; ++b) {
    float s = scaled ? coefs4[b * 32 + t * 4] : 1.f;
    const float* Arow = Ab + (size_t)b * lda + iLoc0;
    for (int kk = threadIdx.x; kk < KC; kk += 256)
      a_s[kk * 20 + b] = s * Arow[kk];
  }
  __syncthreads();

  const int j0 = (blockIdx.y * 256 + threadIdx.x) * VEC;
  const float* Brow = Bb + j0;

  float acc[16][VEC];
#pragma unroll
  for (int b = 0; b < 16; ++b)
#pragma unroll
    for (int v = 0; v < VEC; ++v) acc[b][v] = 0.f;

  float w0[UF][VEC], w1[UF][VEC];

  auto loadg = [&](float (&W)[UF][VEC], int kb) {
#pragma unroll
    for (int u = 0; u < UF; ++u) {
      const float* p = Brow + (size_t)(kb + u) * N;
      if constexpr (VEC == 1) { W[u][0] = p[0]; }
      else { float2 t2 = *reinterpret_cast<const float2*>(p); W[u][0] = t2.x; W[u][1] = t2.y; }
    }
  };
  auto comp = [&](const float (&W)[UF][VEC], int kb) {
#pragma unroll
    for (int u = 0; u < UF; ++u) {
      int kk = kb + u;
      const float4 a0 = *reinterpret_cast<const float4*>(&a_s[kk * 20 + 0]);
      const float4 a1 = *reinterpret_cast<const float4*>(&a_s[kk * 20 + 4]);
      const float4 a2 = *reinterpret_cast<const float4*>(&a_s[kk * 20 + 8]);
      const float4 a3 = *reinterpret_cast<const float4*>(&a_s[kk * 20 + 12]);
      const float av[16] = {a0.x, a0.y, a0.z, a0.w, a1.x, a1.y, a1.z, a1.w,
                            a2.x, a2.y, a2.z, a2.w, a3.x, a3.y, a3.z, a3.w};
#pragma unroll
      for (int b = 0; b < 16; ++b)
#pragma unroll
        for (int v = 0; v < VEC; ++v)
          acc[b][v] = fmaf(av[b], W[u][v], acc[b][v]);
    }
  };

  // Software pipeline, handles even and odd NG at compile time.
  loadg(w0, 0);
  if constexpr (NG % 2 == 0) {
#pragma unroll 1
    for (int g = 0; g + 2 < NG; g += 2) {
      loadg(w1, (g + 1) * UF);
      comp(w0, g * UF);
      loadg(w0, (g + 2) * UF);
      comp(w1, (g + 1) * UF);
    }
    loadg(w1, (NG - 1) * UF);
    comp(w0, (NG - 2) * UF);
    comp(w1, (NG - 1) * UF);
  } else {
#pragma unroll 1
    for (int g = 0; g + 3 < NG; g += 2) {
      loadg(w1, (g + 1) * UF);
      comp(w0, g * UF);
      loadg(w0, (g + 2) * UF);
      comp(w1, (g + 1) * UF);
    }
    loadg(w1, (NG - 2) * UF);
    comp(w0, (NG - 3) * UF);
    loadg(w0, (NG - 1) * UF);
    comp(w1, (NG - 2) * UF);
    comp(w0, (NG - 1) * UF);
  }

  float* Pb = P + (size_t)c * 16 * N + j0;
#pragma unroll
  for (int b = 0; b < 16; ++b) {
    if constexpr (VEC == 1) { Pb[0] = acc[b][0]; }
    else { *reinterpret_cast<float2*>(Pb) = make_float2(acc[b][0], acc[b][1]); }
    Pb += N;
  }
}

// ---------------- fused one-stage reduce + epilogue ----------------
// P: [NCH][Ftot] partials. Block = 256 threads = 32 f-columns x 8 slices.
// Each thread sums NCH/8 chunks; LDS-combine; 32 threads apply epilogue.
// MODE 1: z1,t1 = (+b1, relu)   MODE 2: base = (+b2)
// MODE 3: h = relu(z1 + sum + sum_t c1*db1)   MODE 4: out = b2 + sum + sum_t c3*db2
template<int NCH, int MODE, int FTOT>
__global__ __launch_bounds__(256) void reduce_fused(
    const float* __restrict__ P,
    const float* __restrict__ bias,       // b1 (M1), b2 (M2,M4), z1 (M3)
    const float* __restrict__ coefs,      // M3/M4
    const float* __restrict__ dvec,       // db1 (M3), db2 (M4)
    float* __restrict__ o1, float* __restrict__ o2)
{
  constexpr int CPS = NCH / 8;
  static_assert(NCH % 8 == 0, "");
  __shared__ float r[8][33];
  const int fl = threadIdx.x & 31, s = threadIdx.x >> 5;
  const int f = blockIdx.x * 32 + fl;

  const float* p = P + (size_t)s * CPS * FTOT + f;
  float sum = 0.f;
#pragma unroll 8
  for (int cc = 0; cc < CPS; ++cc) { sum += *p; p += FTOT; }
  r[s][fl] = sum;
  __syncthreads();

  if (s == 0) {
    float v = r[0][fl] + r[1][fl] + r[2][fl] + r[3][fl]
            + r[4][fl] + r[5][fl] + r[6][fl] + r[7][fl];
    if constexpr (MODE == 1) {
      float z = v + bias[f & 1023];
      o1[f] = z;
      o2[f] = fmaxf(z, 0.f);
    } else if constexpr (MODE == 2) {
      o1[f] = v + bias[f & 511];
    } else if constexpr (MODE == 3) {
      int b = f >> 10, j = f & 1023;
      float z = v + bias[f];          // bias = z1
#pragma unroll
      for (int t = 0; t < 8; ++t) z = fmaf(coefs[b * 32 + t * 4 + 1], dvec[t * 1024 + j], z);
      o1[f] = fmaxf(z, 0.f);
    } else {
      int b = f >> 9, k = f & 511;
      float z = v + bias[k];          // bias = b2
#pragma unroll
      for (int t = 0; t < 8; ++t) z = fmaf(coefs[b * 32 + t * 4 + 3], dvec[t * 512 + k], z);
      o1[f] = z;
    }
  }
}

// coefs = (relu(base@mW1+mb1))@mW2+mb2, one block of 1024
__global__ __launch_bounds__(1024) void mcoef_kernel(
    const float* __restrict__ base, const float* __restrict__ mW1, const float* __restrict__ mb1,
    const float* __restrict__ mW2, const float* __restrict__ mb2, float* __restrict__ coefs) {
  __shared__ float bs[16 * 512];
  __shared__ float ms[16 * 128];
  int tid = threadIdx.x;
  for (int i = tid; i < 8192; i += 1024) bs[i] = base[i];
  __syncthreads();
#pragma unroll
  for (int p = 0; p < 2; ++p) {
    int o = p * 1024 + tid;          // 2048 outputs of m
    int b = o >> 7, col = o & 127;
    float acc = mb1[col];
    const float* br = &bs[b * 512];
    for (int k = 0; k < 512; ++k) acc = fmaf(br[k], mW1[k * 128 + col], acc);
    ms[o] = fmaxf(acc, 0.f);
  }
  __syncthreads();
  if (tid < 512) {
    int b = tid >> 5, o = tid & 31;
    float acc = mb2[o];
    const float* mr = &ms[b * 128];
    for (int k = 0; k < 128; ++k) acc = fmaf(mr[k], mW2[k * 32 + o], acc);
    coefs[b * 32 + o] = acc;
  }
}

extern "C" void kernel_launch(void* const* d_in, const int* in_sizes, int n_in,
                              void* d_out, int out_size, void* d_ws, size_t ws_size,
                              hipStream_t stream) {
  const float* x   = (const float*)d_in[0];
  const float* W1  = (const float*)d_in[1];
  const float* b1  = (const float*)d_in[2];
  const float* W2  = (const float*)d_in[3];
  const float* b2  = (const float*)d_in[4];
  const float* dW1 = (const float*)d_in[5];
  const float* db1 = (const float*)d_in[6];
  const float* dW2 = (const float*)d_in[7];
  const float* db2 = (const float*)d_in[8];
  const float* mW1 = (const float*)d_in[9];
  const float* mb1 = (const float*)d_in[10];
  const float* mW2 = (const float*)d_in[11];
  const float* mb2 = (const float*)d_in[12];
  float* out = (float*)d_out;

  float* ws    = (float*)d_ws;
  float* xp    = ws;                 // 150528
  float* z1    = xp + 150528;        // 16384
  float* t1    = z1 + 16384;         // 16384
  float* base  = t1 + 16384;         // 8192
  float* coefs = base + 8192;        // 512
  float* h     = coefs + 512;        // 16384
  float* P1    = h + 16384;          // 192*16*1024 = 3145728
  float* P2    = P1 + 3145728;       // 32*16*512   = 262144
  float* P3    = P2 + 262144;        // 256*16*1024 = 4194304
  float* P4    = P3 + 4194304;       // 288*16*512  = 2359296
  // total ~10.2M floats ~ 41 MB of ws

  const int BIG = 1 << 30;

  // xp = pool(x)
  pool_kernel<<<588, 256, 0, stream>>>(x, xp);

  // z1/t1 = xp @ W1 + b1; relu.  K=9408, KC=49 -> 192 chunks, 4 j-groups -> 768 blocks (3.00/CU)
  skinny_gemm<49, 1, 7><<<dim3(192, 4), 256, 0, stream>>>(
      xp, 9408, W1, nullptr, 0, nullptr, BIG, 0, nullptr, 1024, P1);
  reduce_fused<192, 1, 16384><<<512, 256, 0, stream>>>(P1, b1, nullptr, nullptr, z1, t1);

  // base = t1 @ W2 + b2.  K=1024, KC=32 -> 32 chunks, 2 j-groups
  skinny_gemm<32, 1, 8><<<dim3(32, 2), 256, 0, stream>>>(
      t1, 1024, W2, nullptr, 0, nullptr, BIG, 0, nullptr, 512, P2);
  reduce_fused<32, 2, 8192><<<256, 256, 0, stream>>>(P2, b2, nullptr, nullptr, base, nullptr);

  // coefs
  mcoef_kernel<<<1, 1024, 0, stream>>>(base, mW1, mb1, mW2, mb2, coefs);

  // hc = sum_{t,i} (cW1[b,t]*xp[b,i]) * dW1[t,i,j]
  // K=75264, KC=294 -> 256 chunks (32 per t), 2 j-groups (float2) -> 512 blocks (2.00/CU)
  skinny_gemm<294, 2, 14><<<dim3(256, 2), 256, 0, stream>>>(
      xp, 9408, dW1, nullptr, 0, nullptr, BIG, 32, coefs /* cW1 */, 1024, P3);
  reduce_fused<256, 3, 16384><<<512, 256, 0, stream>>>(P3, z1, coefs, db1, h, nullptr);

  // out_pre = sum_{t,j}(cW2[b,t]*h[b,j])*dW2[t,j,k] + h@W2
  // seg1: 256 chunks (KC=32, 32/t) over dW2 scaled; seg2: 32 chunks over W2
  skinny_gemm<32, 1, 8><<<dim3(288, 2), 256, 0, stream>>>(
      h, 1024, dW2, h, 1024, W2, 256, 32, coefs + 2 /* cW2 */, 512, P4);
  reduce_fused<288, 4, 8192><<<256, 256, 0, stream>>>(P4, b2, coefs, db2, out, nullptr);
}